// Round 1
// baseline (516.709 us; speedup 1.0000x reference)
//
#include <hip/hip_runtime.h>
#include <hip/hip_bf16.h>
#include <math.h>

#define NUM_ENT 100000
#define DIM 768
#define BATCH 4096
#define INV_TAU 20.0f

typedef __attribute__((ext_vector_type(8))) short short8;   // 8 x bf16 (4 VGPRs)
typedef __attribute__((ext_vector_type(4))) float f32x4;    // MFMA accum

// ---------------- Kernel 1: gather + L2-normalize -> bf16 -------------------
__global__ __launch_bounds__(256) void gather_norm(
    const float* __restrict__ emb, const int* __restrict__ links,
    __hip_bfloat16* __restrict__ hn1, __hip_bfloat16* __restrict__ hn2)
{
    int rowId = blockIdx.x;          // 0 .. 2*BATCH-1
    int b     = rowId >> 1;
    int which = rowId & 1;
    int src   = links[2 * b + which];
    const float* srcRow = emb + (size_t)src * DIM;

    int t = threadIdx.x;
    float4 v = make_float4(0.f, 0.f, 0.f, 0.f);
    float ss = 0.f;
    if (t < DIM / 4) {               // 192 threads load float4 each
        v = ((const float4*)srcRow)[t];
        ss = v.x * v.x + v.y * v.y + v.z * v.z + v.w * v.w;
    }
    // wave reduce (64 lanes)
    #pragma unroll
    for (int off = 32; off >= 1; off >>= 1) ss += __shfl_xor(ss, off);
    __shared__ float wsum[4];
    if ((t & 63) == 0) wsum[t >> 6] = ss;
    __syncthreads();
    float tot = wsum[0] + wsum[1] + wsum[2] + wsum[3];
    float scale = 1.0f / sqrtf(tot);

    if (t < DIM / 4) {
        __hip_bfloat16* dst = (which ? hn2 : hn1) + (size_t)b * DIM;
        union { ushort4 u; __hip_bfloat16 h[4]; } o;
        o.h[0] = __float2bfloat16(v.x * scale);
        o.h[1] = __float2bfloat16(v.y * scale);
        o.h[2] = __float2bfloat16(v.z * scale);
        o.h[3] = __float2bfloat16(v.w * scale);
        ((ushort4*)dst)[t] = o.u;
    }
}

// ------- Kernel 2: fused gram (bf16 MFMA) + exp row-sum + diag capture ------
// grid: (8 col-strips, 32 row-tiles, 4 matrices). block: 256 (4 waves).
// matId 0: h1 x h2^T (cross; capture diag) -> S[0]
// matId 1: h1 x h1^T (self; mask diag)     -> S[0]
// matId 2: h2 x h1^T (cross)               -> S[1]
// matId 3: h2 x h2^T (self; mask diag)     -> S[1]
__global__ __launch_bounds__(256) void gram_lse(
    const __hip_bfloat16* __restrict__ hn1, const __hip_bfloat16* __restrict__ hn2,
    float* __restrict__ S, float* __restrict__ diag)
{
    const int strip  = blockIdx.x;
    const int rowTil = blockIdx.y;
    const int matId  = blockIdx.z;

    const __hip_bfloat16* A  = (matId <= 1) ? hn1 : hn2;
    const __hip_bfloat16* Bm = (matId == 1 || matId == 2) ? hn1 : hn2;
    const int  target    = matId >> 1;
    const bool maskDiag  = (matId & 1);
    const bool writeDiag = (matId == 0);

    __shared__ short sA[128 * 32];
    __shared__ short sB[128 * 32];

    const int t    = threadIdx.x;
    const int lane = t & 63;
    const int wave = t >> 6;
    const int wm   = wave >> 1, wn = wave & 1;
    const int quad = lane >> 4, l16 = lane & 15;
    const int row0 = rowTil * 128;

    for (int ct = 0; ct < 4; ++ct) {
        const int col0 = strip * 512 + ct * 128;

        f32x4 acc[4][4];
        #pragma unroll
        for (int im = 0; im < 4; ++im)
            #pragma unroll
            for (int jn = 0; jn < 4; ++jn)
                acc[im][jn] = (f32x4){0.f, 0.f, 0.f, 0.f};

        for (int kk = 0; kk < DIM; kk += 32) {
            // stage 128x32 bf16 tiles of A and B via direct global->LDS, 16B/lane
            #pragma unroll
            for (int i = 0; i < 2; ++i) {
                int c  = i * 256 + t;          // chunk 0..511
                int r  = c >> 2;               // tile row
                int k8 = (c & 3) * 8;          // k offset within 32
                const __hip_bfloat16* ga = A  + (size_t)(row0 + r) * DIM + kk + k8;
                const __hip_bfloat16* gb = Bm + (size_t)(col0 + r) * DIM + kk + k8;
                __builtin_amdgcn_global_load_lds(
                    (const __attribute__((address_space(1))) void*)ga,
                    (__attribute__((address_space(3))) void*)(sA + c * 8), 16, 0, 0);
                __builtin_amdgcn_global_load_lds(
                    (const __attribute__((address_space(1))) void*)gb,
                    (__attribute__((address_space(3))) void*)(sB + c * 8), 16, 0, 0);
            }
            __syncthreads();

            short8 af[4], bfr[4];
            #pragma unroll
            for (int im = 0; im < 4; ++im)
                af[im] = *(const short8*)&sA[(wm * 64 + im * 16 + l16) * 32 + quad * 8];
            #pragma unroll
            for (int jn = 0; jn < 4; ++jn)
                bfr[jn] = *(const short8*)&sB[(wn * 64 + jn * 16 + l16) * 32 + quad * 8];

            #pragma unroll
            for (int im = 0; im < 4; ++im)
                #pragma unroll
                for (int jn = 0; jn < 4; ++jn)
                    acc[im][jn] = __builtin_amdgcn_mfma_f32_16x16x32_bf16(
                        af[im], bfr[jn], acc[im][jn], 0, 0, 0);
            __syncthreads();
        }

        // epilogue: logits = dot/tau; exp; row-sum; diag capture/mask
        #pragma unroll
        for (int im = 0; im < 4; ++im) {
            #pragma unroll
            for (int r = 0; r < 4; ++r) {
                const int gi = row0 + wm * 64 + im * 16 + quad * 4 + r;
                float rsum = 0.f;
                #pragma unroll
                for (int jn = 0; jn < 4; ++jn) {
                    const int gj = col0 + wn * 64 + jn * 16 + l16;
                    float logit = acc[im][jn][r] * INV_TAU;
                    bool isDiag = (gi == gj);
                    if (writeDiag && isDiag) diag[gi] = logit;
                    float e = __expf(logit);
                    if (maskDiag && isDiag) e = 0.f;
                    rsum += e;
                }
                // reduce across the 16 lanes holding this row's 16 columns
                rsum += __shfl_xor(rsum, 1);
                rsum += __shfl_xor(rsum, 2);
                rsum += __shfl_xor(rsum, 4);
                rsum += __shfl_xor(rsum, 8);
                if (l16 == 0) atomicAdd(&S[target * BATCH + gi], rsum);
            }
        }
    }
}

// ---------------- Kernel 3: finalize loss (single block) --------------------
__global__ __launch_bounds__(256) void finalize(
    const float* __restrict__ S, const float* __restrict__ diag,
    float* __restrict__ out)
{
    int t = threadIdx.x;
    float local = 0.f;
    for (int i = t; i < BATCH; i += 256) {
        float lse_a = logf(S[i]);
        float lse_b = logf(S[BATCH + i]);
        local += 0.5f * (lse_a + lse_b) - diag[i];
    }
    #pragma unroll
    for (int off = 32; off >= 1; off >>= 1) local += __shfl_xor(local, off);
    __shared__ float wsum[4];
    if ((t & 63) == 0) wsum[t >> 6] = local;
    __syncthreads();
    if (t == 0) out[0] = (wsum[0] + wsum[1] + wsum[2] + wsum[3]) / (float)BATCH;
}

extern "C" void kernel_launch(void* const* d_in, const int* in_sizes, int n_in,
                              void* d_out, int out_size, void* d_ws, size_t ws_size,
                              hipStream_t stream)
{
    const float* emb  = (const float*)d_in[0];
    const int* links  = (const int*)d_in[1];

    char* ws = (char*)d_ws;
    __hip_bfloat16* hn1 = (__hip_bfloat16*)ws;                              // 6.29 MB
    __hip_bfloat16* hn2 = (__hip_bfloat16*)(ws + (size_t)BATCH * DIM * 2);  // 6.29 MB
    float* S    = (float*)(ws + (size_t)BATCH * DIM * 4);                   // 2*4096 f32
    float* diag = (float*)(ws + (size_t)BATCH * DIM * 4 + 2 * BATCH * 4);   // 4096 f32

    hipMemsetAsync(S, 0, 2 * BATCH * sizeof(float), stream);

    gather_norm<<<dim3(2 * BATCH), 256, 0, stream>>>(emb, links, hn1, hn2);
    gram_lse<<<dim3(8, 32, 4), 256, 0, stream>>>(hn1, hn2, S, diag);
    finalize<<<1, 256, 0, stream>>>(S, diag, (float*)d_out);
}

// Round 2
// 445.650 us; speedup vs baseline: 1.1595x; 1.1595x over previous
//
#include <hip/hip_runtime.h>
#include <hip/hip_bf16.h>
#include <math.h>

#define NUM_ENT 100000
#define DIM 768
#define BATCH 4096
#define INV_TAU 20.0f

typedef __attribute__((ext_vector_type(8))) short short8;   // 8 x bf16 (4 VGPRs)
typedef __attribute__((ext_vector_type(4))) float f32x4;    // MFMA accum

// ---------------- Kernel 1: gather + L2-normalize -> bf16 -------------------
__global__ __launch_bounds__(256) void gather_norm(
    const float* __restrict__ emb, const int* __restrict__ links,
    __hip_bfloat16* __restrict__ hn1, __hip_bfloat16* __restrict__ hn2)
{
    int rowId = blockIdx.x;          // 0 .. 2*BATCH-1
    int b     = rowId >> 1;
    int which = rowId & 1;
    int src   = links[2 * b + which];
    const float* srcRow = emb + (size_t)src * DIM;

    int t = threadIdx.x;
    float4 v = make_float4(0.f, 0.f, 0.f, 0.f);
    float ss = 0.f;
    if (t < DIM / 4) {               // 192 threads load float4 each
        v = ((const float4*)srcRow)[t];
        ss = v.x * v.x + v.y * v.y + v.z * v.z + v.w * v.w;
    }
    #pragma unroll
    for (int off = 32; off >= 1; off >>= 1) ss += __shfl_xor(ss, off);
    __shared__ float wsum[4];
    if ((t & 63) == 0) wsum[t >> 6] = ss;
    __syncthreads();
    float tot = wsum[0] + wsum[1] + wsum[2] + wsum[3];
    float scale = 1.0f / sqrtf(tot);

    if (t < DIM / 4) {
        __hip_bfloat16* dst = (which ? hn2 : hn1) + (size_t)b * DIM;
        union { ushort4 u; __hip_bfloat16 h[4]; } o;
        o.h[0] = __float2bfloat16(v.x * scale);
        o.h[1] = __float2bfloat16(v.y * scale);
        o.h[2] = __float2bfloat16(v.z * scale);
        o.h[3] = __float2bfloat16(v.w * scale);
        ((ushort4*)dst)[t] = o.u;
    }
}

// ------- Kernel 2: symmetric gram (bf16 MFMA) + exp row/col-sum -------------
// grid: (32 colTile, 32 rowTile, 3 matrices). block: 256 (4 waves).
// matId 0: ab = h1 x h2^T  full     : rowsum->S_a, colsum->S_b (= ba rowsum), diag capture
// matId 1: aa = h1 x h1^T  upper-tri: rowsum->S_a[gi]; off-diag tiles also colsum->S_a[gj]
// matId 2: bb = h2 x h2^T  upper-tri: rowsum->S_b[gi]; off-diag tiles also colsum->S_b[gj]
__global__ __launch_bounds__(256) void gram_sym(
    const __hip_bfloat16* __restrict__ hn1, const __hip_bfloat16* __restrict__ hn2,
    float* __restrict__ S, float* __restrict__ diag)
{
    const int ct = blockIdx.x;
    const int rt = blockIdx.y;
    const int matId = blockIdx.z;
    if (matId > 0 && ct < rt) return;   // symmetric matrices: upper triangle only

    const __hip_bfloat16* A  = (matId == 2) ? hn2 : hn1;
    const __hip_bfloat16* Bm = (matId == 1) ? hn1 : hn2;
    const int  rowTarget = (matId == 2) ? 1 : 0;
    const int  colTarget = (matId == 1) ? 0 : 1;
    const bool maskDiag  = (matId > 0) && (rt == ct);
    const bool doColsum  = (matId == 0) || (rt != ct);
    const bool captureDiag = (matId == 0);

    __shared__ short sA[128 * 32];
    __shared__ short sB[128 * 32];

    const int t    = threadIdx.x;
    const int lane = t & 63;
    const int wave = t >> 6;
    const int wm   = wave >> 1, wn = wave & 1;
    const int quad = lane >> 4, l16 = lane & 15;
    const int row0 = rt * 128;
    const int col0 = ct * 128;

    f32x4 acc[4][4];
    #pragma unroll
    for (int im = 0; im < 4; ++im)
        #pragma unroll
        for (int jn = 0; jn < 4; ++jn)
            acc[im][jn] = (f32x4){0.f, 0.f, 0.f, 0.f};

    for (int kk = 0; kk < DIM; kk += 32) {
        // stage 128x32 bf16 tiles; 16 B/lane direct global->LDS.
        // K-chunk position swizzled by (row>>1) so fragment ds_read_b128 is
        // bank-conflict-free (each 8-lane phase covers all 32 banks once).
        #pragma unroll
        for (int i = 0; i < 2; ++i) {
            int c  = i * 256 + t;              // LDS chunk 0..511 (lane-contiguous)
            int r  = c >> 2;                   // tile row
            int s  = c & 3;                    // slot within row
            int q8 = (((s - (r >> 1)) & 3)) * 8;   // source k-chunk (swizzled)
            const __hip_bfloat16* ga = A  + (size_t)(row0 + r) * DIM + kk + q8;
            const __hip_bfloat16* gb = Bm + (size_t)(col0 + r) * DIM + kk + q8;
            __builtin_amdgcn_global_load_lds(
                (const __attribute__((address_space(1))) void*)ga,
                (__attribute__((address_space(3))) void*)(sA + c * 8), 16, 0, 0);
            __builtin_amdgcn_global_load_lds(
                (const __attribute__((address_space(1))) void*)gb,
                (__attribute__((address_space(3))) void*)(sB + c * 8), 16, 0, 0);
        }
        __syncthreads();

        short8 af[4], bfr[4];
        #pragma unroll
        for (int im = 0; im < 4; ++im) {
            int row = wm * 64 + im * 16 + l16;
            int slot = (quad + (row >> 1)) & 3;
            af[im] = *(const short8*)&sA[row * 32 + slot * 8];
        }
        #pragma unroll
        for (int jn = 0; jn < 4; ++jn) {
            int row = wn * 64 + jn * 16 + l16;
            int slot = (quad + (row >> 1)) & 3;
            bfr[jn] = *(const short8*)&sB[row * 32 + slot * 8];
        }

        #pragma unroll
        for (int im = 0; im < 4; ++im)
            #pragma unroll
            for (int jn = 0; jn < 4; ++jn)
                acc[im][jn] = __builtin_amdgcn_mfma_f32_16x16x32_bf16(
                    af[im], bfr[jn], acc[im][jn], 0, 0, 0);
        __syncthreads();
    }

    // epilogue: logits = dot/tau; exp; row sums (+ col sums); diag capture/mask
    float csum[4] = {0.f, 0.f, 0.f, 0.f};
    #pragma unroll
    for (int im = 0; im < 4; ++im) {
        #pragma unroll
        for (int r = 0; r < 4; ++r) {
            const int gi = row0 + wm * 64 + im * 16 + quad * 4 + r;
            float rsum = 0.f;
            #pragma unroll
            for (int jn = 0; jn < 4; ++jn) {
                const int gj = col0 + wn * 64 + jn * 16 + l16;
                float logit = acc[im][jn][r] * INV_TAU;
                bool isDiag = (gi == gj);
                if (captureDiag && isDiag) diag[gi] = logit;
                float e = __expf(logit);
                if (maskDiag && isDiag) e = 0.f;
                rsum += e;
                csum[jn] += e;
            }
            rsum += __shfl_xor(rsum, 1);
            rsum += __shfl_xor(rsum, 2);
            rsum += __shfl_xor(rsum, 4);
            rsum += __shfl_xor(rsum, 8);
            if (l16 == 0) atomicAdd(&S[rowTarget * BATCH + gi], rsum);
        }
    }
    if (doColsum) {
        #pragma unroll
        for (int jn = 0; jn < 4; ++jn) {
            float c = csum[jn];
            c += __shfl_xor(c, 16);
            c += __shfl_xor(c, 32);
            if (quad == 0) {
                const int gj = col0 + wn * 64 + jn * 16 + l16;
                atomicAdd(&S[colTarget * BATCH + gj], c);
            }
        }
    }
}

// ---------------- Kernel 3: finalize loss (single block) --------------------
__global__ __launch_bounds__(256) void finalize(
    const float* __restrict__ S, const float* __restrict__ diag,
    float* __restrict__ out)
{
    int t = threadIdx.x;
    float local = 0.f;
    for (int i = t; i < BATCH; i += 256) {
        float lse_a = logf(S[i]);
        float lse_b = logf(S[BATCH + i]);
        local += 0.5f * (lse_a + lse_b) - diag[i];
    }
    #pragma unroll
    for (int off = 32; off >= 1; off >>= 1) local += __shfl_xor(local, off);
    __shared__ float wsum[4];
    if ((t & 63) == 0) wsum[t >> 6] = local;
    __syncthreads();
    if (t == 0) out[0] = (wsum[0] + wsum[1] + wsum[2] + wsum[3]) / (float)BATCH;
}

extern "C" void kernel_launch(void* const* d_in, const int* in_sizes, int n_in,
                              void* d_out, int out_size, void* d_ws, size_t ws_size,
                              hipStream_t stream)
{
    const float* emb  = (const float*)d_in[0];
    const int* links  = (const int*)d_in[1];

    char* ws = (char*)d_ws;
    __hip_bfloat16* hn1 = (__hip_bfloat16*)ws;                              // 6.29 MB
    __hip_bfloat16* hn2 = (__hip_bfloat16*)(ws + (size_t)BATCH * DIM * 2);  // 6.29 MB
    float* S    = (float*)(ws + (size_t)BATCH * DIM * 4);                   // 2*4096 f32
    float* diag = (float*)(ws + (size_t)BATCH * DIM * 4 + 2 * BATCH * 4);   // 4096 f32

    hipMemsetAsync(S, 0, 2 * BATCH * sizeof(float), stream);

    gather_norm<<<dim3(2 * BATCH), 256, 0, stream>>>(emb, links, hn1, hn2);
    gram_sym<<<dim3(32, 32, 3), 256, 0, stream>>>(hn1, hn2, S, diag);
    finalize<<<1, 256, 0, stream>>>(S, diag, (float*)d_out);
}